// Round 13
// baseline (138.576 us; speedup 1.0000x reference)
//
#include <hip/hip_runtime.h>
#include <stdint.h>

#define T_ 256
#define B_ 8
#define E_ 512
#define H_ 32
#define HD_ 16
#define EXP_ 512
#define S_ 768          // T_ + EXP_
#define M_ 2048         // T_ * B_
#define SMOOTH_ 20.0f
#define PSTR 40         // P-tile LDS row stride (bf16)
#define VSTR 800        // V^T LDS row stride (bf16)
#define LOG2E_ 1.44269504f
#define MB0_  (-100.988655f)   // -70 * log2e

typedef __attribute__((ext_vector_type(8)))  short bf16x8;
typedef __attribute__((ext_vector_type(4)))  float f32x4;
typedef __attribute__((ext_vector_type(16))) float f32x16;

// round-half-up pack: two fp32 -> dword of two bf16 (lo=a, hi=b)
__device__ __forceinline__ unsigned int pku(float a, float b)
{
    return ((__float_as_uint(a) + 0x8000u) >> 16) |
           ((__float_as_uint(b) + 0x8000u) & 0xFFFF0000u);
}
__device__ __forceinline__ ushort bf1(float a)   // RNE
{
    unsigned int u = __float_as_uint(a);
    u = u + 0x7FFFu + ((u >> 16) & 1u);
    return (ushort)(u >> 16);
}

union U16 { uint4 u; bf16x8 v; };

// ---------------------------------------------------------------------------
// Fused QKV-GEMM + attention. One block per (b,h), 512 threads / 8 waves.
// Phase A: M=256(t) x N=48 (Q|K|V head slice) x K=512 GEMM, BK=64,
//   fp32->bf16 conversion in staging; results land in LDS images
//   Qi[256][16], Ks[768][16] (rows 0..255), Vt[16][VSTR] (cols 0..255).
// Expansion: LDS->LDS row gathers via oc fill Ks/Vt rows/cols 256..767.
// Phase B: v9 attention, wave w = t-tile [32w,32w+32), full S per wave
//   (no cross-wave combine). s-on-lanes scores, coalesced law, exp2 softmax.
// ---------------------------------------------------------------------------
__global__ __launch_bounds__(512)
void qkv_attn_kernel(const float* __restrict__ X,
                     const float* __restrict__ Wq, const float* __restrict__ Wk,
                     const float* __restrict__ Wv,
                     const float* __restrict__ bq, const float* __restrict__ bv,
                     const float* __restrict__ LAW,
                     const int* __restrict__ kpm, const int* __restrict__ em,
                     const int* __restrict__ oc, ushort* __restrict__ Ab)
{
    __shared__ __align__(16) char raw[82944];
    ushort* Ks  = (ushort*)(raw);            // 768*16 bf16   = 24576 B
    ushort* Vt  = (ushort*)(raw + 24576);    // 16*VSTR bf16  = 25600 B
    ushort* Qi  = (ushort*)(raw + 50176);    // 256*16 bf16   =  8192 B
    float*  msf = (float*) (raw + 58368);    // 768 f32       =  3072 B
    ushort* Pbb = (ushort*)(raw + 61440);    // 8*32*PSTR     = 20480 B
    float*  Zb  = (float*) (raw + 81920);    // 8*32 f32      =  1024 B
    ushort* As  = (ushort*)(raw);            // phase A alias: 256*72 = 36864 B
    ushort* Bs  = (ushort*)(raw + 36864);    // phase A alias: 48*72  =  6912 B
    ushort* Ob  = Qi;                        // epilogue alias (Qi dead)

    const int bh  = blockIdx.x;
    const int b   = bh >> 5;
    const int h   = bh & 31;
    const int tid = threadIdx.x;
    const int w   = tid >> 6;
    const int l   = tid & 63;

    // ======================= Phase A: QKV GEMM =======================
    const int lr = tid >> 1;          // t row 0..255
    const int kq = tid & 1;           // 32-float k half
    const float* Xr = &X[((size_t)lr * 8 + b) * E_ + kq * 32];
    const int wr = tid >> 3;          // 0..47 (valid tid<384): mat=wr>>4, d=wr&15
    const int wk = tid & 7;           // 8-float chunk
    const float* Wsel = (wr < 16) ? Wq : (wr < 32 ? Wk : Wv);
    const float* Wr = &Wsel[((size_t)(h * 16 + (wr & 15))) * E_ + wk * 8];
    const bool wload = (tid < 384);   // wave-uniform (waves 0..5)

    ushort* Axw = &As[lr * 72 + kq * 32];
    ushort* Bxw = &Bs[wr * 72 + wk * 8];

    f32x4 acc[2][3];
#pragma unroll
    for (int i = 0; i < 2; ++i)
#pragma unroll
        for (int m = 0; m < 3; ++m)
            acc[i][m] = (f32x4){0.f, 0.f, 0.f, 0.f};

    float4 xp[8], wp[2];
#pragma unroll
    for (int j = 0; j < 8; ++j) xp[j] = *(const float4*)&Xr[j * 4];
    if (wload) { wp[0] = *(const float4*)&Wr[0]; wp[1] = *(const float4*)&Wr[4]; }

    const int ln = l & 15;
    const int lg = l >> 4;

    for (int it = 0; it < 8; ++it) {
        __syncthreads();
#pragma unroll
        for (int g = 0; g < 4; ++g)
            *(uint4*)&Axw[g * 8] = make_uint4(
                pku(xp[2*g].x, xp[2*g].y),   pku(xp[2*g].z, xp[2*g].w),
                pku(xp[2*g+1].x, xp[2*g+1].y), pku(xp[2*g+1].z, xp[2*g+1].w));
        if (wload)
            *(uint4*)&Bxw[0] = make_uint4(pku(wp[0].x, wp[0].y), pku(wp[0].z, wp[0].w),
                                          pku(wp[1].x, wp[1].y), pku(wp[1].z, wp[1].w));
        __syncthreads();
        if (it < 7) {
            Xr += 64;
#pragma unroll
            for (int j = 0; j < 8; ++j) xp[j] = *(const float4*)&Xr[j * 4];
            if (wload) { Wr += 64; wp[0] = *(const float4*)&Wr[0]; wp[1] = *(const float4*)&Wr[4]; }
        }
#pragma unroll
        for (int kb = 0; kb < 2; ++kb) {
            bf16x8 af0 = *(const bf16x8*)&As[(32 * w + ln) * 72 + kb * 32 + lg * 8];
            bf16x8 af1 = *(const bf16x8*)&As[(32 * w + 16 + ln) * 72 + kb * 32 + lg * 8];
#pragma unroll
            for (int m = 0; m < 3; ++m) {
                bf16x8 bfm = *(const bf16x8*)&Bs[(m * 16 + ln) * 72 + kb * 32 + lg * 8];
                acc[0][m] = __builtin_amdgcn_mfma_f32_16x16x32_bf16(af0, bfm, acc[0][m], 0, 0, 0);
                acc[1][m] = __builtin_amdgcn_mfma_f32_16x16x32_bf16(af1, bfm, acc[1][m], 0, 0, 0);
            }
        }
    }

    __syncthreads();   // As/Bs dead; image region may be written

    // ---- write Q/K/V images (C-layout: col=ln=d, row=lg*4+r=t_local) ----
    {
        const float bqv = bq[h * 16 + ln];
        const float bvv = bv[h * 16 + ln];
#pragma unroll
        for (int i = 0; i < 2; ++i)
#pragma unroll
            for (int r = 0; r < 4; ++r) {
                const int t = 32 * w + 16 * i + lg * 4 + r;
                Qi[t * 16 + ln]    = bf1(acc[i][0][r] + bqv);
                Ks[t * 16 + ln]    = bf1(acc[i][1][r]);
                Vt[ln * VSTR + t]  = bf1(acc[i][2][r] + bvv);
            }
    }
    __syncthreads();

    // ---- expansion rows/cols 256..767 (LDS->LDS) + masks ----
    {
        const int j   = tid;
        const int src = oc[b * EXP_ + j];
        uint4 k0 = *(const uint4*)&Ks[src * 16];
        uint4 k1 = *(const uint4*)&Ks[src * 16 + 8];
        *(uint4*)&Ks[(T_ + j) * 16]     = k0;
        *(uint4*)&Ks[(T_ + j) * 16 + 8] = k1;
#pragma unroll
        for (int d = 0; d < 16; ++d)
            Vt[d * VSTR + T_ + j] = Vt[d * VSTR + src];

        const int s = tid;
        const int m = (s < T_) ? kpm[b * T_ + s] : em[b * EXP_ + (s - T_)];
        msf[s] = m ? -1.0e5f : MB0_;
        if (tid < 256) {
            const int s2 = 512 + tid;
            msf[s2] = em[b * EXP_ + (s2 - T_)] ? -1.0e5f : MB0_;
        }
    }
    __syncthreads();

    // ======================= Phase B: attention =======================
    const int slane = l & 31;
    const int khalf = l >> 5;
    const int tl = l & 15;
    const int kg = l >> 4;

    bf16x8 qf = *(const bf16x8*)&Qi[(w * 32 + slane) * 16 + khalf * 8];

    const f32x16 zero16 = {0.f,0.f,0.f,0.f,0.f,0.f,0.f,0.f,
                           0.f,0.f,0.f,0.f,0.f,0.f,0.f,0.f};
    f32x4 o0 = {0.f, 0.f, 0.f, 0.f};
    f32x4 o1 = {0.f, 0.f, 0.f, 0.f};
    float zacc[16];
#pragma unroll
    for (int r = 0; r < 16; ++r) zacc[r] = 0.f;

    const float* lawb = &LAW[((size_t)b * T_ + w * 32 + khalf * 4) * S_ + slane];
    ushort* pw = &Pbb[w * 32 * PSTR + slane];
    ushort* pt = &Pbb[w * 32 * PSTR];

    for (int i = 0; i < S_ / 32; ++i) {
        bf16x8 kf = *(const bf16x8*)&Ks[(i * 32 + slane) * 16 + khalf * 8];

        float lw[16];
        const float* lp = lawb + i * 32;
#pragma unroll
        for (int r = 0; r < 16; ++r)
            lw[r] = lp[(size_t)((r & 3) + 8 * (r >> 2)) * S_];

        f32x16 sc = __builtin_amdgcn_mfma_f32_32x32x16_bf16(qf, kf, zero16, 0, 0, 0);
        const float mb = msf[i * 32 + slane];

#pragma unroll
        for (int r = 0; r < 16; ++r) {
            const float lwK = lw[r] * LOG2E_;
            const float arg = __builtin_fmaf(sc[r], lwK,
                              __builtin_fmaf(lwK, SMOOTH_, mb));
            const float e = __builtin_amdgcn_exp2f(arg);
            zacc[r] += e;
            const float p = e * lw[r];
            pw[((r & 3) + 8 * (r >> 2) + 4 * khalf) * PSTR] =
                (ushort)((__float_as_uint(p) + 0x8000u) >> 16);
        }

        bf16x8 vf = *(const bf16x8*)&Vt[tl * VSTR + i * 32 + kg * 8];
        {
            const ushort* pr0 = &pt[(0 * 16 + tl) * PSTR + kg * 8];
            U16 u;
            uint2 a0 = *(const uint2*)pr0;
            uint2 a1 = *(const uint2*)(pr0 + 4);
            u.u = make_uint4(a0.x, a0.y, a1.x, a1.y);
            o0 = __builtin_amdgcn_mfma_f32_16x16x32_bf16(vf, u.v, o0, 0, 0, 0);
            const ushort* pr1 = &pt[(1 * 16 + tl) * PSTR + kg * 8];
            uint2 b0 = *(const uint2*)pr1;
            uint2 b1 = *(const uint2*)(pr1 + 4);
            u.u = make_uint4(b0.x, b0.y, b1.x, b1.y);
            o1 = __builtin_amdgcn_mfma_f32_16x16x32_bf16(vf, u.v, o1, 0, 0, 0);
        }
    }

    // Z reduce within the 32-lane s-groups (khalf halves independent)
#pragma unroll
    for (int m = 1; m < 32; m <<= 1) {
#pragma unroll
        for (int r = 0; r < 16; ++r)
            zacc[r] += __shfl_xor(zacc[r], m);
    }
    if (l == 0 || l == 32) {
#pragma unroll
        for (int r = 0; r < 16; ++r)
            Zb[w * 32 + (r & 3) + 8 * (r >> 2) + 4 * khalf] = zacc[r];
    }
    __syncthreads();

    // epilogue: divide, pack to Ob (aliases Qi; all qf loads are long done)
#pragma unroll
    for (int th = 0; th < 2; ++th) {
        const int trow = th * 16 + tl;
        const float Zt  = Zb[w * 32 + trow];
        const float inv = (Zt > 0.f) ? 1.f / Zt : 0.f;
        const f32x4 o = th ? o1 : o0;
        const int t = w * 32 + trow;
        *(uint*)&Ob[t * 16 + kg * 4]     = pku(o[0] * inv, o[1] * inv);
        *(uint*)&Ob[t * 16 + kg * 4 + 2] = pku(o[2] * inv, o[3] * inv);
    }
    __syncthreads();

    // coalesced store: one contiguous 8 KB region per block
    {
        ushort* dp = &Ab[((size_t)(b * H_ + h)) * T_ * HD_];
        *(uint4*)&dp[tid * 8] = *(const uint4*)&Ob[tid * 8];
    }
}

// ---------------------------------------------------------------------------
// out GEMM (unchanged from round 12): A = Ab bf16 [b][h][t][16], B = Wo fp32.
// ---------------------------------------------------------------------------
template<bool AF, bool BF>
__device__ __forceinline__ void gemm_body(const void* __restrict__ Xp, int xstep,
                                          const void* __restrict__ Wp, int wstep,
                                          f32x4 acc[2][2],
                                          ushort* As, ushort* Bs)
{
    const int tid  = threadIdx.x;
    const int lrow = tid >> 2;
    const int kq   = tid & 3;
    const int l    = tid & 63;
    const int w    = tid >> 6;
    const int wm   = w & 1;
    const int wn   = w >> 1;
    const int lq   = l >> 4;
    const int ln   = l & 15;

    ushort* Aw = &As[lrow * 72 + kq * 16];
    ushort* Bw = &Bs[lrow * 72 + kq * 16];

    const ushort* Xh = (const ushort*)Xp;
    const float*  Wf = (const float*)Wp;

    uint4  ha0 = *(const uint4*)&Xh[0];
    uint4  ha1 = *(const uint4*)&Xh[8];
    float4 fb0 = *(const float4*)&Wf[0];
    float4 fb1 = *(const float4*)&Wf[4];
    float4 fb2 = *(const float4*)&Wf[8];
    float4 fb3 = *(const float4*)&Wf[12];

    for (int it = 0; it < E_ / 64; ++it) {
        __syncthreads();
        *(uint4*)&Aw[0] = ha0;
        *(uint4*)&Aw[8] = ha1;
        *(uint4*)&Bw[0] = make_uint4(pku(fb0.x, fb0.y), pku(fb0.z, fb0.w),
                                     pku(fb1.x, fb1.y), pku(fb1.z, fb1.w));
        *(uint4*)&Bw[8] = make_uint4(pku(fb2.x, fb2.y), pku(fb2.z, fb2.w),
                                     pku(fb3.x, fb3.y), pku(fb3.z, fb3.w));
        __syncthreads();
        if (it < E_ / 64 - 1) {
            Xh += xstep;
            ha0 = *(const uint4*)&Xh[0];
            ha1 = *(const uint4*)&Xh[8];
            Wf += wstep;
            fb0 = *(const float4*)&Wf[0];
            fb1 = *(const float4*)&Wf[4];
            fb2 = *(const float4*)&Wf[8];
            fb3 = *(const float4*)&Wf[12];
        }
#pragma unroll
        for (int kb = 0; kb < 2; ++kb) {
            bf16x8 af0 = *(const bf16x8*)&As[(32 * wm + ln) * 72 + 32 * kb + lq * 8];
            bf16x8 af1 = *(const bf16x8*)&As[(32 * wm + 16 + ln) * 72 + 32 * kb + lq * 8];
            bf16x8 bf0 = *(const bf16x8*)&Bs[(32 * wn + ln) * 72 + 32 * kb + lq * 8];
            bf16x8 bf1 = *(const bf16x8*)&Bs[(32 * wn + 16 + ln) * 72 + 32 * kb + lq * 8];
            acc[0][0] = __builtin_amdgcn_mfma_f32_16x16x32_bf16(af0, bf0, acc[0][0], 0, 0, 0);
            acc[0][1] = __builtin_amdgcn_mfma_f32_16x16x32_bf16(af0, bf1, acc[0][1], 0, 0, 0);
            acc[1][0] = __builtin_amdgcn_mfma_f32_16x16x32_bf16(af1, bf0, acc[1][0], 0, 0, 0);
            acc[1][1] = __builtin_amdgcn_mfma_f32_16x16x32_bf16(af1, bf1, acc[1][1], 0, 0, 0);
        }
    }
}

__global__ __launch_bounds__(256)
void out_gemm(const ushort* __restrict__ Ab, const float* __restrict__ Wo,
              const float* __restrict__ bo, float* __restrict__ dst)
{
    __shared__ __align__(16) ushort AsBs[2 * 64 * 72];
    ushort* As = AsBs;
    ushort* Bs = AsBs + 64 * 72;

    const int m0 = blockIdx.y * 64;
    const int n0 = blockIdx.x * 64;

    f32x4 acc[2][2];
#pragma unroll
    for (int i = 0; i < 2; ++i)
#pragma unroll
        for (int j = 0; j < 2; ++j)
            acc[i][j] = (f32x4){0.f, 0.f, 0.f, 0.f};

    const int tid  = threadIdx.x;
    const int lrow = tid >> 2;
    const int kq   = tid & 3;
    const int m    = m0 + lrow;
    const int t    = m >> 3;
    const int b    = m & 7;
    gemm_body<false, true>(&Ab[(((size_t)(b * H_ + kq)) * T_ + t) * HD_], 4 * T_ * HD_,
                           &Wo[(size_t)(n0 + lrow) * E_ + kq * 16], 64,
                           acc, As, Bs);

    const int l  = tid & 63;
    const int w  = tid >> 6;
    const int wm = w & 1;
    const int wn = w >> 1;
    const int lq = l >> 4;
    const int ln = l & 15;

    const float bo0 = bo[n0 + 32 * wn + ln];
    const float bo1 = bo[n0 + 32 * wn + 16 + ln];

    __syncthreads();
    float* Lf = (float*)AsBs;
#pragma unroll
    for (int j = 0; j < 2; ++j) {
        const float bb = j ? bo1 : bo0;
#pragma unroll
        for (int i = 0; i < 2; ++i)
#pragma unroll
            for (int r = 0; r < 4; ++r)
                Lf[(32 * wm + 16 * i + lq * 4 + r) * 68 + 32 * wn + 16 * j + ln] =
                    acc[i][j][r] + bb;
    }
    __syncthreads();

    {
        const int lm = tid & 63;
        const int hh = tid >> 6;
        float* dp = &dst[(size_t)(m0 + lm) * E_ + n0 + hh * 16];
#pragma unroll
        for (int c = 0; c < 4; ++c) {
            float4 v = *(const float4*)&Lf[lm * 68 + hh * 16 + c * 4];
            *(float4*)&dp[c * 4] = v;
        }
    }
}

// ---------------------------------------------------------------------------
extern "C" void kernel_launch(void* const* d_in, const int* in_sizes, int n_in,
                              void* d_out, int out_size, void* d_ws, size_t ws_size,
                              hipStream_t stream)
{
    const float* query = (const float*)d_in[0];
    const int*   oc    = (const int*)d_in[1];
    const int*   em    = (const int*)d_in[2];
    const int*   kpm   = (const int*)d_in[3];
    const float* law   = (const float*)d_in[4];
    const float* Wq    = (const float*)d_in[5];
    const float* bq    = (const float*)d_in[6];
    const float* Wk    = (const float*)d_in[7];
    const float* Wv    = (const float*)d_in[8];
    const float* bv    = (const float*)d_in[9];
    const float* Wo    = (const float*)d_in[10];
    const float* bo    = (const float*)d_in[11];
    float* out = (float*)d_out;

    ushort* Ab = (ushort*)d_ws;     // [b][h][t][16] bf16

    qkv_attn_kernel<<<B_ * H_, 512, 0, stream>>>(query, Wq, Wk, Wv, bq, bv,
                                                 law, kpm, em, oc, Ab);

    dim3 go(E_ / 64, M_ / 64, 1);
    out_gemm<<<go, 256, 0, stream>>>(Ab, Wo, bo, out);
}

// Round 14
// 129.091 us; speedup vs baseline: 1.0735x; 1.0735x over previous
//
#include <hip/hip_runtime.h>
#include <stdint.h>

#define T_ 256
#define B_ 8
#define E_ 512
#define H_ 32
#define HD_ 16
#define EXP_ 512
#define S_ 768          // T_ + EXP_
#define M_ 2048         // T_ * B_
#define SMOOTH_ 20.0f
#define PSTR 40         // P-tile LDS row stride (bf16): khalf groups -> disjoint bank halves
#define VSTR 800        // V^T LDS row stride (bf16)
#define LOG2E_ 1.44269504f
#define MB0_  (-100.988655f)   // -70 * log2e

typedef __attribute__((ext_vector_type(8)))  short bf16x8;
typedef __attribute__((ext_vector_type(4)))  float f32x4;
typedef __attribute__((ext_vector_type(16))) float f32x16;

// round-half-up pack: two fp32 -> dword of two bf16 (lo=a, hi=b)
__device__ __forceinline__ unsigned int pku(float a, float b)
{
    return ((__float_as_uint(a) + 0x8000u) >> 16) |
           ((__float_as_uint(b) + 0x8000u) & 0xFFFF0000u);
}
__device__ __forceinline__ ushort bf1(float a)   // RNE
{
    unsigned int u = __float_as_uint(a);
    u = u + 0x7FFFu + ((u >> 16) & 1u);
    return (ushort)(u >> 16);
}

union U16 { uint4 u; bf16x8 v; };

// ---------------------------------------------------------------------------
// Fused QKV-GEMM + attention. One block per (b,h), 512 threads / 8 waves.
// LDS = exactly 81920 B -> 2 blocks/CU (163840 = full 160 KB).
// Phase A: M=256(t) x N=48 (Q|K|V slice) x K=512, BK=64; X staged with
//   coalesced (row=tid>>3 + 64k, c8=tid&7) pattern: 8x256B contiguous
//   segments per wave inst (was 64x16B).  fp32->bf16 fused in staging.
// Phase B: v9 attention per 32-t wave tile, full S, no cross-wave combine.
// ---------------------------------------------------------------------------
__global__ __launch_bounds__(512, 4)
void qkv_attn_kernel(const float* __restrict__ X,
                     const float* __restrict__ Wq, const float* __restrict__ Wk,
                     const float* __restrict__ Wv,
                     const float* __restrict__ bq, const float* __restrict__ bv,
                     const float* __restrict__ LAW,
                     const int* __restrict__ kpm, const int* __restrict__ em,
                     const int* __restrict__ oc, ushort* __restrict__ Ab)
{
    __shared__ __align__(16) char raw[81920];
    ushort* Ks  = (ushort*)(raw);            // 768*16 bf16   = 24576 B
    ushort* Vt  = (ushort*)(raw + 24576);    // 16*VSTR bf16  = 25600 B
    ushort* Qi  = (ushort*)(raw + 50176);    // 256*16 bf16   =  8192 B
    float*  msf = (float*) (raw + 58368);    // 768 f32       =  3072 B
    ushort* Pbb = (ushort*)(raw + 61440);    // 8*32*PSTR     = 20480 B -> 81920
    ushort* As  = (ushort*)(raw);            // phase A alias: 256*72 = 36864 B
    ushort* Bs  = (ushort*)(raw + 36864);    // phase A alias: 48*72  =  6912 B
    ushort* Ob  = Qi;                        // epilogue alias (Qi dead)

    const int bh  = blockIdx.x;
    const int b   = bh >> 5;
    const int h   = bh & 31;
    const int tid = threadIdx.x;
    const int w   = tid >> 6;
    const int l   = tid & 63;

    // ======================= Phase A: QKV GEMM =======================
    const int r0 = tid >> 3;          // base t-row 0..63 (rows r0 + 64k)
    const int c8 = tid & 7;           // 8-float chunk within the 64-k tile
    const float* Xc = &X[((size_t)r0 * 8 + b) * E_ + c8 * 8];

    const int wr = tid >> 3;          // 0..47 valid (tid<384): mat=wr>>4, d=wr&15
    const int wk = tid & 7;
    const float* Wsel = (wr < 16) ? Wq : (wr < 32 ? Wk : Wv);
    const float* Wr = &Wsel[((size_t)(h * 16 + (wr & 15))) * E_ + wk * 8];
    const bool wload = (tid < 384);   // wave-uniform (waves 0..5)

    ushort* Bxw = &Bs[wr * 72 + wk * 8];

    f32x4 acc[2][3];
#pragma unroll
    for (int i = 0; i < 2; ++i)
#pragma unroll
        for (int m = 0; m < 3; ++m)
            acc[i][m] = (f32x4){0.f, 0.f, 0.f, 0.f};

    float4 xp[4][2], wp[2];
#pragma unroll
    for (int k = 0; k < 4; ++k) {
        xp[k][0] = *(const float4*)&Xc[(size_t)k * 262144];
        xp[k][1] = *(const float4*)&Xc[(size_t)k * 262144 + 4];
    }
    if (wload) { wp[0] = *(const float4*)&Wr[0]; wp[1] = *(const float4*)&Wr[4]; }

    const int ln = l & 15;
    const int lg = l >> 4;

    for (int it = 0; it < 8; ++it) {
        __syncthreads();
#pragma unroll
        for (int k = 0; k < 4; ++k)
            *(uint4*)&As[(r0 + 64 * k) * 72 + c8 * 8] = make_uint4(
                pku(xp[k][0].x, xp[k][0].y), pku(xp[k][0].z, xp[k][0].w),
                pku(xp[k][1].x, xp[k][1].y), pku(xp[k][1].z, xp[k][1].w));
        if (wload)
            *(uint4*)&Bxw[0] = make_uint4(pku(wp[0].x, wp[0].y), pku(wp[0].z, wp[0].w),
                                          pku(wp[1].x, wp[1].y), pku(wp[1].z, wp[1].w));
        __syncthreads();
        if (it < 7) {
            Xc += 64;
#pragma unroll
            for (int k = 0; k < 4; ++k) {
                xp[k][0] = *(const float4*)&Xc[(size_t)k * 262144];
                xp[k][1] = *(const float4*)&Xc[(size_t)k * 262144 + 4];
            }
            if (wload) { Wr += 64; wp[0] = *(const float4*)&Wr[0]; wp[1] = *(const float4*)&Wr[4]; }
        }
#pragma unroll
        for (int kb = 0; kb < 2; ++kb) {
            bf16x8 af0 = *(const bf16x8*)&As[(32 * w + ln) * 72 + kb * 32 + lg * 8];
            bf16x8 af1 = *(const bf16x8*)&As[(32 * w + 16 + ln) * 72 + kb * 32 + lg * 8];
#pragma unroll
            for (int m = 0; m < 3; ++m) {
                bf16x8 bfm = *(const bf16x8*)&Bs[(m * 16 + ln) * 72 + kb * 32 + lg * 8];
                acc[0][m] = __builtin_amdgcn_mfma_f32_16x16x32_bf16(af0, bfm, acc[0][m], 0, 0, 0);
                acc[1][m] = __builtin_amdgcn_mfma_f32_16x16x32_bf16(af1, bfm, acc[1][m], 0, 0, 0);
            }
        }
    }

    __syncthreads();   // As/Bs dead; image region may be written

    // ---- write Q/K/V images (C-layout: col=ln=d, row=lg*4+r=t_local) ----
    {
        const float bqv = bq[h * 16 + ln];
        const float bvv = bv[h * 16 + ln];
#pragma unroll
        for (int i = 0; i < 2; ++i)
#pragma unroll
            for (int r = 0; r < 4; ++r) {
                const int t = 32 * w + 16 * i + lg * 4 + r;
                Qi[t * 16 + ln]    = bf1(acc[i][0][r] + bqv);
                Ks[t * 16 + ln]    = bf1(acc[i][1][r]);
                Vt[ln * VSTR + t]  = bf1(acc[i][2][r] + bvv);
            }
    }
    __syncthreads();

    // ---- expansion rows/cols 256..767 (LDS->LDS) + masks ----
    {
        const int j   = tid;
        const int src = oc[b * EXP_ + j];
        uint4 k0 = *(const uint4*)&Ks[src * 16];
        uint4 k1 = *(const uint4*)&Ks[src * 16 + 8];
        *(uint4*)&Ks[(T_ + j) * 16]     = k0;
        *(uint4*)&Ks[(T_ + j) * 16 + 8] = k1;
#pragma unroll
        for (int d = 0; d < 16; ++d)
            Vt[d * VSTR + T_ + j] = Vt[d * VSTR + src];

        const int s = tid;
        const int m = (s < T_) ? kpm[b * T_ + s] : em[b * EXP_ + (s - T_)];
        msf[s] = m ? -1.0e5f : MB0_;
        if (tid < 256) {
            const int s2 = 512 + tid;
            msf[s2] = em[b * EXP_ + (s2 - T_)] ? -1.0e5f : MB0_;
        }
    }
    __syncthreads();

    // ======================= Phase B: attention =======================
    const int slane = l & 31;
    const int khalf = l >> 5;
    const int tl = l & 15;
    const int kg = l >> 4;

    bf16x8 qf = *(const bf16x8*)&Qi[(w * 32 + slane) * 16 + khalf * 8];

    const f32x16 zero16 = {0.f,0.f,0.f,0.f,0.f,0.f,0.f,0.f,
                           0.f,0.f,0.f,0.f,0.f,0.f,0.f,0.f};
    f32x4 o0 = {0.f, 0.f, 0.f, 0.f};
    f32x4 o1 = {0.f, 0.f, 0.f, 0.f};
    float zacc[16];
#pragma unroll
    for (int r = 0; r < 16; ++r) zacc[r] = 0.f;

    const float* lawb = &LAW[((size_t)b * T_ + w * 32 + khalf * 4) * S_ + slane];
    ushort* pw = &Pbb[w * 32 * PSTR + slane];
    ushort* pt = &Pbb[w * 32 * PSTR];
    float*  Zbw = (float*)pt;          // per-wave Z buffer aliased on own dead P tile

    for (int i = 0; i < S_ / 32; ++i) {
        bf16x8 kf = *(const bf16x8*)&Ks[(i * 32 + slane) * 16 + khalf * 8];

        float lw[16];
        const float* lp = lawb + i * 32;
#pragma unroll
        for (int r = 0; r < 16; ++r)
            lw[r] = lp[(size_t)((r & 3) + 8 * (r >> 2)) * S_];

        f32x16 sc = __builtin_amdgcn_mfma_f32_32x32x16_bf16(qf, kf, zero16, 0, 0, 0);
        const float mb = msf[i * 32 + slane];

#pragma unroll
        for (int r = 0; r < 16; ++r) {
            const float lwK = lw[r] * LOG2E_;
            const float arg = __builtin_fmaf(sc[r], lwK,
                              __builtin_fmaf(lwK, SMOOTH_, mb));
            const float e = __builtin_amdgcn_exp2f(arg);
            zacc[r] += e;
            const float p = e * lw[r];
            pw[((r & 3) + 8 * (r >> 2) + 4 * khalf) * PSTR] =
                (ushort)((__float_as_uint(p) + 0x8000u) >> 16);
        }

        bf16x8 vf = *(const bf16x8*)&Vt[tl * VSTR + i * 32 + kg * 8];
        {
            const ushort* pr0 = &pt[(0 * 16 + tl) * PSTR + kg * 8];
            U16 u;
            uint2 a0 = *(const uint2*)pr0;
            uint2 a1 = *(const uint2*)(pr0 + 4);
            u.u = make_uint4(a0.x, a0.y, a1.x, a1.y);
            o0 = __builtin_amdgcn_mfma_f32_16x16x32_bf16(vf, u.v, o0, 0, 0, 0);
            const ushort* pr1 = &pt[(1 * 16 + tl) * PSTR + kg * 8];
            uint2 b0 = *(const uint2*)pr1;
            uint2 b1 = *(const uint2*)(pr1 + 4);
            u.u = make_uint4(b0.x, b0.y, b1.x, b1.y);
            o1 = __builtin_amdgcn_mfma_f32_16x16x32_bf16(vf, u.v, o1, 0, 0, 0);
        }
    }

    // Z reduce within the 32-lane s-groups (khalf halves independent)
#pragma unroll
    for (int m = 1; m < 32; m <<= 1) {
#pragma unroll
        for (int r = 0; r < 16; ++r)
            zacc[r] += __shfl_xor(zacc[r], m);
    }
    if (l == 0 || l == 32) {       // own wave's P tile is dead; wave-local
#pragma unroll
        for (int r = 0; r < 16; ++r)
            Zbw[(r & 3) + 8 * (r >> 2) + 4 * khalf] = zacc[r];
    }
    __syncthreads();               // all waves done: qf long consumed, Ob safe

    // epilogue: divide, pack to Ob (aliases Qi)
#pragma unroll
    for (int th = 0; th < 2; ++th) {
        const int trow = th * 16 + tl;
        const float Zt  = Zbw[trow];
        const float inv = (Zt > 0.f) ? 1.f / Zt : 0.f;
        const f32x4 o = th ? o1 : o0;
        const int t = w * 32 + trow;
        *(uint*)&Ob[t * 16 + kg * 4]     = pku(o[0] * inv, o[1] * inv);
        *(uint*)&Ob[t * 16 + kg * 4 + 2] = pku(o[2] * inv, o[3] * inv);
    }
    __syncthreads();

    // coalesced store: one contiguous 8 KB region per block
    {
        ushort* dp = &Ab[((size_t)(b * H_ + h)) * T_ * HD_];
        *(uint4*)&dp[tid * 8] = *(const uint4*)&Ob[tid * 8];
    }
}

// ---------------------------------------------------------------------------
// out GEMM (unchanged): A = Ab bf16 [b][h][t][16], B = Wo fp32 (fused cvt).
// ---------------------------------------------------------------------------
__device__ __forceinline__ void out_gemm_body(const ushort* __restrict__ Xh, int xstep,
                                              const float* __restrict__ Wf, int wstep,
                                              f32x4 acc[2][2],
                                              ushort* As, ushort* Bs)
{
    const int tid  = threadIdx.x;
    const int lrow = tid >> 2;
    const int kq   = tid & 3;
    const int l    = tid & 63;
    const int w    = tid >> 6;
    const int wm   = w & 1;
    const int wn   = w >> 1;
    const int lq   = l >> 4;
    const int ln   = l & 15;

    ushort* Aw = &As[lrow * 72 + kq * 16];
    ushort* Bw = &Bs[lrow * 72 + kq * 16];

    uint4  ha0 = *(const uint4*)&Xh[0];
    uint4  ha1 = *(const uint4*)&Xh[8];
    float4 fb0 = *(const float4*)&Wf[0];
    float4 fb1 = *(const float4*)&Wf[4];
    float4 fb2 = *(const float4*)&Wf[8];
    float4 fb3 = *(const float4*)&Wf[12];

    for (int it = 0; it < E_ / 64; ++it) {
        __syncthreads();
        *(uint4*)&Aw[0] = ha0;
        *(uint4*)&Aw[8] = ha1;
        *(uint4*)&Bw[0] = make_uint4(pku(fb0.x, fb0.y), pku(fb0.z, fb0.w),
                                     pku(fb1.x, fb1.y), pku(fb1.z, fb1.w));
        *(uint4*)&Bw[8] = make_uint4(pku(fb2.x, fb2.y), pku(fb2.z, fb2.w),
                                     pku(fb3.x, fb3.y), pku(fb3.z, fb3.w));
        __syncthreads();
        if (it < E_ / 64 - 1) {
            Xh += xstep;
            ha0 = *(const uint4*)&Xh[0];
            ha1 = *(const uint4*)&Xh[8];
            Wf += wstep;
            fb0 = *(const float4*)&Wf[0];
            fb1 = *(const float4*)&Wf[4];
            fb2 = *(const float4*)&Wf[8];
            fb3 = *(const float4*)&Wf[12];
        }
#pragma unroll
        for (int kb = 0; kb < 2; ++kb) {
            bf16x8 af0 = *(const bf16x8*)&As[(32 * wm + ln) * 72 + 32 * kb + lq * 8];
            bf16x8 af1 = *(const bf16x8*)&As[(32 * wm + 16 + ln) * 72 + 32 * kb + lq * 8];
            bf16x8 bf0 = *(const bf16x8*)&Bs[(32 * wn + ln) * 72 + 32 * kb + lq * 8];
            bf16x8 bf1 = *(const bf16x8*)&Bs[(32 * wn + 16 + ln) * 72 + 32 * kb + lq * 8];
            acc[0][0] = __builtin_amdgcn_mfma_f32_16x16x32_bf16(af0, bf0, acc[0][0], 0, 0, 0);
            acc[0][1] = __builtin_amdgcn_mfma_f32_16x16x32_bf16(af0, bf1, acc[0][1], 0, 0, 0);
            acc[1][0] = __builtin_amdgcn_mfma_f32_16x16x32_bf16(af1, bf0, acc[1][0], 0, 0, 0);
            acc[1][1] = __builtin_amdgcn_mfma_f32_16x16x32_bf16(af1, bf1, acc[1][1], 0, 0, 0);
        }
    }
}

__global__ __launch_bounds__(256)
void out_gemm(const ushort* __restrict__ Ab, const float* __restrict__ Wo,
              const float* __restrict__ bo, float* __restrict__ dst)
{
    __shared__ __align__(16) ushort AsBs[2 * 64 * 72];
    ushort* As = AsBs;
    ushort* Bs = AsBs + 64 * 72;

    const int m0 = blockIdx.y * 64;
    const int n0 = blockIdx.x * 64;

    f32x4 acc[2][2];
#pragma unroll
    for (int i = 0; i < 2; ++i)
#pragma unroll
        for (int j = 0; j < 2; ++j)
            acc[i][j] = (f32x4){0.f, 0.f, 0.f, 0.f};

    const int tid  = threadIdx.x;
    const int lrow = tid >> 2;
    const int kq   = tid & 3;
    const int m    = m0 + lrow;
    const int t    = m >> 3;
    const int b    = m & 7;
    out_gemm_body(&Ab[(((size_t)(b * H_ + kq)) * T_ + t) * HD_], 4 * T_ * HD_,
                  &Wo[(size_t)(n0 + lrow) * E_ + kq * 16], 64,
                  acc, As, Bs);

    const int l  = tid & 63;
    const int w  = tid >> 6;
    const int wm = w & 1;
    const int wn = w >> 1;
    const int lq = l >> 4;
    const int ln = l & 15;

    const float bo0 = bo[n0 + 32 * wn + ln];
    const float bo1 = bo[n0 + 32 * wn + 16 + ln];

    __syncthreads();
    float* Lf = (float*)AsBs;
#pragma unroll
    for (int j = 0; j < 2; ++j) {
        const float bb = j ? bo1 : bo0;
#pragma unroll
        for (int i = 0; i < 2; ++i)
#pragma unroll
            for (int r = 0; r < 4; ++r)
                Lf[(32 * wm + 16 * i + lq * 4 + r) * 68 + 32 * wn + 16 * j + ln] =
                    acc[i][j][r] + bb;
    }
    __syncthreads();

    {
        const int lm = tid & 63;
        const int hh = tid >> 6;
        float* dp = &dst[(size_t)(m0 + lm) * E_ + n0 + hh * 16];
#pragma unroll
        for (int c = 0; c < 4; ++c) {
            float4 v = *(const float4*)&Lf[lm * 68 + hh * 16 + c * 4];
            *(float4*)&dp[c * 4] = v;
        }
    }
}

// ---------------------------------------------------------------------------
extern "C" void kernel_launch(void* const* d_in, const int* in_sizes, int n_in,
                              void* d_out, int out_size, void* d_ws, size_t ws_size,
                              hipStream_t stream)
{
    const float* query = (const float*)d_in[0];
    const int*   oc    = (const int*)d_in[1];
    const int*   em    = (const int*)d_in[2];
    const int*   kpm   = (const int*)d_in[3];
    const float* law   = (const float*)d_in[4];
    const float* Wq    = (const float*)d_in[5];
    const float* bq    = (const float*)d_in[6];
    const float* Wk    = (const float*)d_in[7];
    const float* Wv    = (const float*)d_in[8];
    const float* bv    = (const float*)d_in[9];
    const float* Wo    = (const float*)d_in[10];
    const float* bo    = (const float*)d_in[11];
    float* out = (float*)d_out;

    ushort* Ab = (ushort*)d_ws;     // [b][h][t][16] bf16

    qkv_attn_kernel<<<B_ * H_, 512, 0, stream>>>(query, Wq, Wk, Wv, bq, bv,
                                                 law, kpm, em, oc, Ab);

    dim3 go(E_ / 64, M_ / 64, 1);
    out_gemm<<<go, 256, 0, stream>>>(Ab, Wo, bo, out);
}

// Round 15
// 123.970 us; speedup vs baseline: 1.1178x; 1.0413x over previous
//
#include <hip/hip_runtime.h>
#include <stdint.h>

#define T_ 256
#define B_ 8
#define E_ 512
#define H_ 32
#define HD_ 16
#define EXP_ 512
#define S_ 768          // T_ + EXP_
#define M_ 2048         // T_ * B_
#define SMOOTH_ 20.0f
#define PSTR 40         // P-tile LDS row stride (bf16)
#define VSTR 800        // V^T LDS row stride (bf16)
#define OSTR 20         // O-combine LDS row stride (f32)
#define LOG2E_ 1.44269504f
#define MB0_  (-100.988655f)   // -70 * log2e

typedef __attribute__((ext_vector_type(8)))  short bf16x8;
typedef __attribute__((ext_vector_type(4)))  float f32x4;
typedef __attribute__((ext_vector_type(16))) float f32x16;

// round-half-up pack: two fp32 -> dword of two bf16 (lo=a, hi=b)
__device__ __forceinline__ unsigned int pku(float a, float b)
{
    return ((__float_as_uint(a) + 0x8000u) >> 16) |
           ((__float_as_uint(b) + 0x8000u) & 0xFFFF0000u);
}
__device__ __forceinline__ ushort bf1(float a)   // RNE
{
    unsigned int u = __float_as_uint(a);
    u = u + 0x7FFFu + ((u >> 16) & 1u);
    return (ushort)(u >> 16);
}

union U16 { uint4 u; bf16x8 v; };

// ---------------------------------------------------------------------------
// Fused QKV-GEMM + attention, v12: one block per (b,h), 1024 threads /
// 16 waves (4 waves/SIMD at 1 block/CU -- 2x round-14 occupancy).
// Phase A: M=256 x N=48 x K=512, BK=64; wave = one m16-tile x all 3 n16
//   tiles (acc = 3 x f32x4, no combine). Coalesced X staging (2 rows/thr).
// Phase B: wave = (t32-tile, s-half); 12 s-iters; cross-s-half (O,Z)
//   combine through Ks/msf aliases (v9 scheme).
// Output Ab is row-major [m][E] bf16 so out_gemm A-staging is coalesced.
// ---------------------------------------------------------------------------
__global__ __launch_bounds__(1024, 4)
void qkv_attn_kernel(const float* __restrict__ X,
                     const float* __restrict__ Wq, const float* __restrict__ Wk,
                     const float* __restrict__ Wv,
                     const float* __restrict__ bq, const float* __restrict__ bv,
                     const float* __restrict__ LAW,
                     const int* __restrict__ kpm, const int* __restrict__ em,
                     const int* __restrict__ oc, ushort* __restrict__ Ab)
{
    __shared__ __align__(16) char raw[102400];
    ushort* Ks  = (ushort*)(raw);            // 768*16 bf16   = 24576 B
    ushort* Vt  = (ushort*)(raw + 24576);    // 16*VSTR bf16  = 25600 B
    ushort* Qi  = (ushort*)(raw + 50176);    // 256*16 bf16   =  8192 B
    float*  msf = (float*) (raw + 58368);    // 768 f32       =  3072 B
    ushort* Pbb = (ushort*)(raw + 61440);    // 16*32*PSTR    = 40960 B -> 102400
    ushort* As  = (ushort*)(raw);            // phase A alias: 256*72 = 36864 B
    ushort* Bs  = (ushort*)(raw + 36864);    // phase A alias: 48*72  =  6912 B
    float*  Obuf= (float*) (raw);            // post-loop alias: 256*OSTR f32 = 20480 B
    float*  Zb  = (float*) (raw + 58368);    // post-loop alias on msf: 2*256 f32
    ushort* Ob  = Qi;                        // epilogue alias (Qi dead)

    const int bh  = blockIdx.x;
    const int b   = bh >> 5;
    const int h   = bh & 31;
    const int tid = threadIdx.x;
    const int w   = tid >> 6;      // 0..15
    const int l   = tid & 63;

    // ======================= Phase A: QKV GEMM =======================
    const int r0 = tid >> 3;          // t-row 0..127 (also covers r0+128)
    const int c8 = tid & 7;           // 8-float chunk in the 64-k tile
    const float* Xc0 = &X[((size_t)r0 * 8 + b) * E_ + c8 * 8];
    const float* Xc1 = Xc0 + (size_t)128 * 8 * E_;

    const int wr = tid >> 3;          // valid < 48 (tid < 384)
    const bool wload = (tid < 384);   // wave-uniform (waves 0..5)
    const float* Wsel = (wr < 16) ? Wq : (wr < 32 ? Wk : Wv);
    const float* Wr = &Wsel[((size_t)(h * 16 + (wr & 15))) * E_ + c8 * 8];
    ushort* Bxw = &Bs[wr * 72 + c8 * 8];

    f32x4 acc[3];
#pragma unroll
    for (int m = 0; m < 3; ++m) acc[m] = (f32x4){0.f, 0.f, 0.f, 0.f};

    float4 xa0, xa1, xb0, xb1, wp0, wp1;
    xa0 = *(const float4*)&Xc0[0]; xa1 = *(const float4*)&Xc0[4];
    xb0 = *(const float4*)&Xc1[0]; xb1 = *(const float4*)&Xc1[4];
    if (wload) { wp0 = *(const float4*)&Wr[0]; wp1 = *(const float4*)&Wr[4]; }

    const int ln = l & 15;
    const int lg = l >> 4;

    for (int it = 0; it < 8; ++it) {
        __syncthreads();
        *(uint4*)&As[r0 * 72 + c8 * 8] =
            make_uint4(pku(xa0.x, xa0.y), pku(xa0.z, xa0.w),
                       pku(xa1.x, xa1.y), pku(xa1.z, xa1.w));
        *(uint4*)&As[(r0 + 128) * 72 + c8 * 8] =
            make_uint4(pku(xb0.x, xb0.y), pku(xb0.z, xb0.w),
                       pku(xb1.x, xb1.y), pku(xb1.z, xb1.w));
        if (wload)
            *(uint4*)&Bxw[0] = make_uint4(pku(wp0.x, wp0.y), pku(wp0.z, wp0.w),
                                          pku(wp1.x, wp1.y), pku(wp1.z, wp1.w));
        __syncthreads();
        if (it < 7) {
            Xc0 += 64; Xc1 += 64;
            xa0 = *(const float4*)&Xc0[0]; xa1 = *(const float4*)&Xc0[4];
            xb0 = *(const float4*)&Xc1[0]; xb1 = *(const float4*)&Xc1[4];
            if (wload) { Wr += 64; wp0 = *(const float4*)&Wr[0]; wp1 = *(const float4*)&Wr[4]; }
        }
#pragma unroll
        for (int kb = 0; kb < 2; ++kb) {
            bf16x8 af = *(const bf16x8*)&As[(w * 16 + ln) * 72 + kb * 32 + lg * 8];
#pragma unroll
            for (int m = 0; m < 3; ++m) {
                bf16x8 bfm = *(const bf16x8*)&Bs[(m * 16 + ln) * 72 + kb * 32 + lg * 8];
                acc[m] = __builtin_amdgcn_mfma_f32_16x16x32_bf16(af, bfm, acc[m], 0, 0, 0);
            }
        }
    }

    __syncthreads();   // As/Bs dead; image region may be written

    // ---- write Q/K/V images (C-layout: col=ln=d, row=lg*4+r) ----
    {
        const float bqv = bq[h * 16 + ln];
        const float bvv = bv[h * 16 + ln];
#pragma unroll
        for (int r = 0; r < 4; ++r) {
            const int t = w * 16 + lg * 4 + r;
            Qi[t * 16 + ln]   = bf1(acc[0][r] + bqv);
            Ks[t * 16 + ln]   = bf1(acc[1][r]);
            Vt[ln * VSTR + t] = bf1(acc[2][r] + bvv);
        }
    }
    __syncthreads();

    // ---- expansion rows/cols 256..767 (LDS->LDS) + masks ----
    if (tid < 512) {
        const int j   = tid;
        const int src = oc[b * EXP_ + j];
        uint4 k0 = *(const uint4*)&Ks[src * 16];
        uint4 k1 = *(const uint4*)&Ks[src * 16 + 8];
        *(uint4*)&Ks[(T_ + j) * 16]     = k0;
        *(uint4*)&Ks[(T_ + j) * 16 + 8] = k1;
    } else {
        const int j   = tid - 512;
        const int src = oc[b * EXP_ + j];
#pragma unroll
        for (int d = 0; d < 16; ++d)
            Vt[d * VSTR + T_ + j] = Vt[d * VSTR + src];
    }
    if (tid < 768) {
        const int s = tid;
        const int m = (s < T_) ? kpm[b * T_ + s] : em[b * EXP_ + (s - T_)];
        msf[s] = m ? -1.0e5f : MB0_;
    }
    __syncthreads();

    // ======================= Phase B: attention =======================
    const int slane = l & 31;
    const int khalf = l >> 5;
    const int tl = l & 15;
    const int kg = l >> 4;
    const int tq = w & 7;          // t32-tile
    const int sh = w >> 3;         // s-half

    bf16x8 qf = *(const bf16x8*)&Qi[(tq * 32 + slane) * 16 + khalf * 8];

    const f32x16 zero16 = {0.f,0.f,0.f,0.f,0.f,0.f,0.f,0.f,
                           0.f,0.f,0.f,0.f,0.f,0.f,0.f,0.f};
    f32x4 o0 = {0.f, 0.f, 0.f, 0.f};
    f32x4 o1 = {0.f, 0.f, 0.f, 0.f};
    float zacc[16];
#pragma unroll
    for (int r = 0; r < 16; ++r) zacc[r] = 0.f;

    const float* lawb = &LAW[((size_t)b * T_ + tq * 32 + khalf * 4) * S_ + slane];
    ushort* pw = &Pbb[w * 32 * PSTR + slane];
    ushort* pt = &Pbb[w * 32 * PSTR];

    for (int i = sh * 12; i < sh * 12 + 12; ++i) {
        bf16x8 kf = *(const bf16x8*)&Ks[(i * 32 + slane) * 16 + khalf * 8];

        float lw[16];
        const float* lp = lawb + i * 32;
#pragma unroll
        for (int r = 0; r < 16; ++r)
            lw[r] = lp[(size_t)((r & 3) + 8 * (r >> 2)) * S_];

        f32x16 sc = __builtin_amdgcn_mfma_f32_32x32x16_bf16(qf, kf, zero16, 0, 0, 0);
        const float mb = msf[i * 32 + slane];

#pragma unroll
        for (int r = 0; r < 16; ++r) {
            const float lwK = lw[r] * LOG2E_;
            const float arg = __builtin_fmaf(sc[r], lwK,
                              __builtin_fmaf(lwK, SMOOTH_, mb));
            const float e = __builtin_amdgcn_exp2f(arg);
            zacc[r] += e;
            const float p = e * lw[r];
            pw[((r & 3) + 8 * (r >> 2) + 4 * khalf) * PSTR] =
                (ushort)((__float_as_uint(p) + 0x8000u) >> 16);
        }

        bf16x8 vf = *(const bf16x8*)&Vt[tl * VSTR + i * 32 + kg * 8];
        {
            const ushort* pr0 = &pt[(0 * 16 + tl) * PSTR + kg * 8];
            U16 u;
            uint2 a0 = *(const uint2*)pr0;
            uint2 a1 = *(const uint2*)(pr0 + 4);
            u.u = make_uint4(a0.x, a0.y, a1.x, a1.y);
            o0 = __builtin_amdgcn_mfma_f32_16x16x32_bf16(vf, u.v, o0, 0, 0, 0);
            const ushort* pr1 = &pt[(1 * 16 + tl) * PSTR + kg * 8];
            uint2 b0 = *(const uint2*)pr1;
            uint2 b1 = *(const uint2*)(pr1 + 4);
            u.u = make_uint4(b0.x, b0.y, b1.x, b1.y);
            o1 = __builtin_amdgcn_mfma_f32_16x16x32_bf16(vf, u.v, o1, 0, 0, 0);
        }
    }

    // reduce zacc across the 32-lane s-groups (khalf halves independent)
#pragma unroll
    for (int m = 1; m < 32; m <<= 1) {
#pragma unroll
        for (int r = 0; r < 16; ++r)
            zacc[r] += __shfl_xor(zacc[r], m);
    }

    __syncthreads();   // all waves past the loop: Ks/msf dead, alias safe

    if (l == 0 || l == 32) {
#pragma unroll
        for (int r = 0; r < 16; ++r)
            Zb[sh * 256 + tq * 32 + (r & 3) + 8 * (r >> 2) + 4 * khalf] = zacc[r];
    }
    if (sh == 1) {
#pragma unroll
        for (int th = 0; th < 2; ++th) {
            const f32x4 o = th ? o1 : o0;
            *(float4*)&Obuf[((size_t)(tq * 32 + th * 16 + tl)) * OSTR + kg * 4] =
                make_float4(o[0], o[1], o[2], o[3]);
        }
    }
    __syncthreads();

    if (sh == 0) {
#pragma unroll
        for (int th = 0; th < 2; ++th) {
            const int t = tq * 32 + th * 16 + tl;
            const float Zt  = Zb[t] + Zb[256 + t];
            const float inv = (Zt > 0.f) ? 1.f / Zt : 0.f;
            float4 po = *(const float4*)&Obuf[(size_t)t * OSTR + kg * 4];
            const f32x4 o = th ? o1 : o0;
            float ov[4] = {(o[0] + po.x) * inv, (o[1] + po.y) * inv,
                           (o[2] + po.z) * inv, (o[3] + po.w) * inv};
            *(uint*)&Ob[t * 16 + kg * 4]     = pku(ov[0], ov[1]);
            *(uint*)&Ob[t * 16 + kg * 4 + 2] = pku(ov[2], ov[3]);
        }
    }
    __syncthreads();

    // store to Ab row-major [m][E]: m = t*8+b, cols h*16..h*16+16
    {
        const int t  = tid >> 2;
        const int q4 = tid & 3;
        *(uint2*)&Ab[((size_t)(t * 8 + b)) * E_ + h * 16 + q4 * 4] =
            *(const uint2*)&Ob[t * 16 + q4 * 4];
    }
}

// ---------------------------------------------------------------------------
// out GEMM: A = Ab bf16 row-major [M][E] (coalesced rows), B = Wo fp32.
// ---------------------------------------------------------------------------
__device__ __forceinline__ void out_gemm_body(const ushort* __restrict__ Xh,
                                              const float* __restrict__ Wf,
                                              f32x4 acc[2][2],
                                              ushort* As, ushort* Bs)
{
    const int tid  = threadIdx.x;
    const int lrow = tid >> 2;
    const int kq   = tid & 3;
    const int l    = tid & 63;
    const int w    = tid >> 6;
    const int wm   = w & 1;
    const int wn   = w >> 1;
    const int lq   = l >> 4;
    const int ln   = l & 15;

    ushort* Aw = &As[lrow * 72 + kq * 16];
    ushort* Bw = &Bs[lrow * 72 + kq * 16];

    uint4  ha0 = *(const uint4*)&Xh[0];
    uint4  ha1 = *(const uint4*)&Xh[8];
    float4 fb0 = *(const float4*)&Wf[0];
    float4 fb1 = *(const float4*)&Wf[4];
    float4 fb2 = *(const float4*)&Wf[8];
    float4 fb3 = *(const float4*)&Wf[12];

    for (int it = 0; it < E_ / 64; ++it) {
        __syncthreads();
        *(uint4*)&Aw[0] = ha0;
        *(uint4*)&Aw[8] = ha1;
        *(uint4*)&Bw[0] = make_uint4(pku(fb0.x, fb0.y), pku(fb0.z, fb0.w),
                                     pku(fb1.x, fb1.y), pku(fb1.z, fb1.w));
        *(uint4*)&Bw[8] = make_uint4(pku(fb2.x, fb2.y), pku(fb2.z, fb2.w),
                                     pku(fb3.x, fb3.y), pku(fb3.z, fb3.w));
        __syncthreads();
        if (it < E_ / 64 - 1) {
            Xh += 64;
            ha0 = *(const uint4*)&Xh[0];
            ha1 = *(const uint4*)&Xh[8];
            Wf += 64;
            fb0 = *(const float4*)&Wf[0];
            fb1 = *(const float4*)&Wf[4];
            fb2 = *(const float4*)&Wf[8];
            fb3 = *(const float4*)&Wf[12];
        }
#pragma unroll
        for (int kb = 0; kb < 2; ++kb) {
            bf16x8 af0 = *(const bf16x8*)&As[(32 * wm + ln) * 72 + 32 * kb + lq * 8];
            bf16x8 af1 = *(const bf16x8*)&As[(32 * wm + 16 + ln) * 72 + 32 * kb + lq * 8];
            bf16x8 bf0 = *(const bf16x8*)&Bs[(32 * wn + ln) * 72 + 32 * kb + lq * 8];
            bf16x8 bf1 = *(const bf16x8*)&Bs[(32 * wn + 16 + ln) * 72 + 32 * kb + lq * 8];
            acc[0][0] = __builtin_amdgcn_mfma_f32_16x16x32_bf16(af0, bf0, acc[0][0], 0, 0, 0);
            acc[0][1] = __builtin_amdgcn_mfma_f32_16x16x32_bf16(af0, bf1, acc[0][1], 0, 0, 0);
            acc[1][0] = __builtin_amdgcn_mfma_f32_16x16x32_bf16(af1, bf0, acc[1][0], 0, 0, 0);
            acc[1][1] = __builtin_amdgcn_mfma_f32_16x16x32_bf16(af1, bf1, acc[1][1], 0, 0, 0);
        }
    }
}

__global__ __launch_bounds__(256)
void out_gemm(const ushort* __restrict__ Ab, const float* __restrict__ Wo,
              const float* __restrict__ bo, float* __restrict__ dst)
{
    __shared__ __align__(16) ushort AsBs[2 * 64 * 72];
    ushort* As = AsBs;
    ushort* Bs = AsBs + 64 * 72;

    const int m0 = blockIdx.y * 64;
    const int n0 = blockIdx.x * 64;

    f32x4 acc[2][2];
#pragma unroll
    for (int i = 0; i < 2; ++i)
#pragma unroll
        for (int j = 0; j < 2; ++j)
            acc[i][j] = (f32x4){0.f, 0.f, 0.f, 0.f};

    const int tid  = threadIdx.x;
    const int lrow = tid >> 2;
    const int kq   = tid & 3;
    out_gemm_body(&Ab[(size_t)(m0 + lrow) * E_ + kq * 16],
                  &Wo[(size_t)(n0 + lrow) * E_ + kq * 16],
                  acc, As, Bs);

    const int l  = tid & 63;
    const int w  = tid >> 6;
    const int wm = w & 1;
    const int wn = w >> 1;
    const int lq = l >> 4;
    const int ln = l & 15;

    const float bo0 = bo[n0 + 32 * wn + ln];
    const float bo1 = bo[n0 + 32 * wn + 16 + ln];

    __syncthreads();
    float* Lf = (float*)AsBs;
#pragma unroll
    for (int j = 0; j < 2; ++j) {
        const float bb = j ? bo1 : bo0;
#pragma unroll
        for (int i = 0; i < 2; ++i)
#pragma unroll
            for (int r = 0; r < 4; ++r)
                Lf[(32 * wm + 16 * i + lq * 4 + r) * 68 + 32 * wn + 16 * j + ln] =
                    acc[i][j][r] + bb;
    }
    __syncthreads();

    {
        const int lm = tid & 63;
        const int hh = tid >> 6;
        float* dp = &dst[(size_t)(m0 + lm) * E_ + n0 + hh * 16];
#pragma unroll
        for (int c = 0; c < 4; ++c) {
            float4 v = *(const float4*)&Lf[lm * 68 + hh * 16 + c * 4];
            *(float4*)&dp[c * 4] = v;
        }
    }
}

// ---------------------------------------------------------------------------
extern "C" void kernel_launch(void* const* d_in, const int* in_sizes, int n_in,
                              void* d_out, int out_size, void* d_ws, size_t ws_size,
                              hipStream_t stream)
{
    const float* query = (const float*)d_in[0];
    const int*   oc    = (const int*)d_in[1];
    const int*   em    = (const int*)d_in[2];
    const int*   kpm   = (const int*)d_in[3];
    const float* law   = (const float*)d_in[4];
    const float* Wq    = (const float*)d_in[5];
    const float* bq    = (const float*)d_in[6];
    const float* Wk    = (const float*)d_in[7];
    const float* Wv    = (const float*)d_in[8];
    const float* bv    = (const float*)d_in[9];
    const float* Wo    = (const float*)d_in[10];
    const float* bo    = (const float*)d_in[11];
    float* out = (float*)d_out;

    ushort* Ab = (ushort*)d_ws;     // row-major [M][E] bf16

    qkv_attn_kernel<<<B_ * H_, 1024, 0, stream>>>(query, Wq, Wk, Wv, bq, bv,
                                                  law, kpm, em, oc, Ab);

    dim3 go(E_ / 64, M_ / 64, 1);
    out_gemm<<<go, 256, 0, stream>>>(Ab, Wo, bo, out);
}